// Round 2
// baseline (3298.746 us; speedup 1.0000x reference)
//
#include <hip/hip_runtime.h>
#include <hip/hip_bf16.h>
#include <hip/hip_fp16.h>

// MetaGIN fused pipeline, round 2: dtype-adaptive (fp32 vs bf16 dataset
// detected on-device from deg's bit pattern), fp16 h-buffers, h0 in d_out.
//
// ws layout (bytes, N=200000):
//   [ agg: N*128 f32 (102.4MB) | h1: N*128 f16 (51.2MB) | params_b16 (~0.5MB) ]
// h0 (N*128 f16) lives in d_out (fully overwritten by k_post at the end).

typedef unsigned short u16;
typedef unsigned int   u32;

#define WIDTH 128

// params_b16 element offsets (all converted to bf16)
#define OFF_W0   0        // 16384
#define OFF_B0   16384    // 128
#define OFF_W1   16512    // 16384
#define OFF_B1   32896    // 128
#define OFF_EMB  33024    // 33*128 = 4224
#define OFF_GW   37248    // 128*16 = 2048
#define OFF_VW   39296    // 2048
#define OFF_PW   41344    // 16384
#define OFF_PB   57728    // 128
#define OFF_DP   57856    // 128
#define OFF_DEG  57984    // N

__device__ __forceinline__ float bfl(u32 p){ return __uint_as_float(p << 16); }
__device__ __forceinline__ float bfh(u32 p){ return __uint_as_float(p & 0xffff0000u); }
__device__ __forceinline__ float b2f(u16 u){ return __uint_as_float(((u32)u) << 16); }
__device__ __forceinline__ u16   f2b(float f){
  u32 u = __float_as_uint(f);
  u += 0x7fffu + ((u >> 16) & 1u);   // RNE
  return (u16)(u >> 16);
}
__device__ __forceinline__ float h2fl(u32 p){ return __half2float(__ushort_as_half((u16)(p & 0xffffu))); }
__device__ __forceinline__ float h2fh(u32 p){ return __half2float(__ushort_as_half((u16)(p >> 16))); }
__device__ __forceinline__ u16   f2h(float f){ return __half_as_ushort(__float2half(f)); }

// deg holds exact integers 1..7. fp32: low16 of word0 == 0. bf16: == deg[0] != 0.
__device__ __forceinline__ bool is_fp32(const void* degsrc){
  return ((*(const u32*)degsrc) & 0xffffu) == 0u;
}

// ---------------------------------------------------------------------------
// k_convert: normalize all small float params (+deg) into bf16 arena.
// ---------------------------------------------------------------------------
__device__ __forceinline__ u16 cvt_one(const void* src, int j, bool f32){
  return f32 ? f2b(((const float*)src)[j]) : ((const u16*)src)[j];
}

__global__ void k_convert(const void* w0, const void* b0, const void* w1, const void* b1,
                          const void* emb, const void* gw, const void* vw,
                          const void* pw, const void* pb, const void* dp,
                          const void* degsrc, u16* __restrict__ pb16, int total)
{
  const int i = blockIdx.x * 256 + threadIdx.x;
  if (i >= total) return;
  const bool f32 = is_fp32(degsrc);
  u16 v;
  if      (i < OFF_B0 ) v = cvt_one(w0,  i,           f32);
  else if (i < OFF_W1 ) v = cvt_one(b0,  i - OFF_B0,  f32);
  else if (i < OFF_B1 ) v = cvt_one(w1,  i - OFF_W1,  f32);
  else if (i < OFF_EMB) v = cvt_one(b1,  i - OFF_B1,  f32);
  else if (i < OFF_GW ) v = cvt_one(emb, i - OFF_EMB, f32);
  else if (i < OFF_VW ) v = cvt_one(gw,  i - OFF_GW,  f32);
  else if (i < OFF_PW ) v = cvt_one(vw,  i - OFF_VW,  f32);
  else if (i < OFF_PB ) v = cvt_one(pw,  i - OFF_PW,  f32);
  else if (i < OFF_DP ) v = cvt_one(pb,  i - OFF_PB,  f32);
  else if (i < OFF_DEG) v = cvt_one(dp,  i - OFF_DP,  f32);
  else                  v = cvt_one(degsrc, i - OFF_DEG, f32);
  pb16[i] = v;
}

// ---------------------------------------------------------------------------
// k_pre: h0 = x@w0^T + b0, h1 = x@w1^T + b1 (f16 out), + zero agg.
// 256 threads: t>>7 selects matrix, t&127 = output channel. Weight row packed
// in 64 u32 VGPRs; x-row loads are block-uniform. 64 nodes/block, 8-node ILP.
// ---------------------------------------------------------------------------
__global__ __launch_bounds__(256, 2) void k_pre(
    const void* __restrict__ x, const u16* __restrict__ pb16,
    u16* __restrict__ h0, u16* __restrict__ h1,
    float* __restrict__ agg, const void* __restrict__ degsrc)
{
  const int t = threadIdx.x;
  const int which = t >> 7;
  const int c = t & 127;
  const int node0 = blockIdx.x * 64;

  // zero this block's agg rows (ws is poisoned 0xAA before every launch)
  {
    float4 z = make_float4(0.f, 0.f, 0.f, 0.f);
    float4* ar = (float4*)(agg + (size_t)node0 * WIDTH);
    #pragma unroll
    for (int i = 0; i < 8; ++i) ar[t + 256 * i] = z;
  }

  const u16* w  = pb16 + (which ? OFF_W1 : OFF_W0);
  u16*     hout = which ? h1 : h0;
  const float bias = b2f(pb16[(which ? OFF_B1 : OFF_B0) + c]);

  u32 wp[64];
  const u32* wrow = (const u32*)(w + (size_t)c * WIDTH);
  #pragma unroll
  for (int k2 = 0; k2 < 64; ++k2) wp[k2] = wrow[k2];

  const bool f32 = is_fp32(degsrc);

  for (int g = 0; g < 8; ++g) {
    float acc[8];
    #pragma unroll
    for (int n = 0; n < 8; ++n) acc[n] = bias;

    if (f32) {
      const float2* xr = (const float2*)((const float*)x + (size_t)(node0 + g * 8) * WIDTH);
      #pragma unroll
      for (int k2 = 0; k2 < 64; ++k2) {
        const float wl = bfl(wp[k2]), wh = bfh(wp[k2]);
        #pragma unroll
        for (int n = 0; n < 8; ++n) {
          float2 xv = xr[n * 64 + k2];               // block-uniform
          acc[n] = fmaf(xv.x, wl, acc[n]);
          acc[n] = fmaf(xv.y, wh, acc[n]);
        }
      }
    } else {
      const u32* xr = (const u32*)((const u16*)x + (size_t)(node0 + g * 8) * WIDTH);
      #pragma unroll
      for (int k2 = 0; k2 < 64; ++k2) {
        const float wl = bfl(wp[k2]), wh = bfh(wp[k2]);
        #pragma unroll
        for (int n = 0; n < 8; ++n) {
          u32 xp = xr[n * 64 + k2];                  // block-uniform
          acc[n] = fmaf(bfl(xp), wl, acc[n]);
          acc[n] = fmaf(bfh(xp), wh, acc[n]);
        }
      }
    }
    #pragma unroll
    for (int n = 0; n < 8; ++n)
      hout[(size_t)(node0 + g * 8 + n) * WIDTH + c] = f2h(acc[n]);
  }
}

// ---------------------------------------------------------------------------
// k_edge: gather h0[src]+h1[dst] (f16) -> GroupNorm(8x16) -> +EmbeddingBag
// mean -> gate=relu(grouped1x1(y)), val=grouped1x1(xn) -> atomicAdd agg[dst].
// 32 threads/edge, 4 ch/lane; GroupNorm via shfl_xor over 4-lane clusters.
// ---------------------------------------------------------------------------
__global__ __launch_bounds__(256, 2) void k_edge(
    const u16* __restrict__ h0, const u16* __restrict__ h1,
    const int* __restrict__ eidx, const int* __restrict__ eattr,
    const u16* __restrict__ pb16,
    float* __restrict__ agg, const int E, const int stride)
{
  const int t    = threadIdx.x;
  const int slot = t >> 5;        // 8 edges per block
  const int q    = t & 31;        // lane within edge; channels 4q..4q+3
  const int g    = q >> 2;        // head (16 ch = 4 lanes)

  const u16* emb = pb16 + OFF_EMB;
  u32 gwp[4][8], vwp[4][8];
  #pragma unroll
  for (int m = 0; m < 4; ++m) {
    const u32* gr = (const u32*)(pb16 + OFF_GW + (size_t)(4 * q + m) * 16);
    const u32* vr = (const u32*)(pb16 + OFF_VW + (size_t)(4 * q + m) * 16);
    #pragma unroll
    for (int i = 0; i < 8; ++i) { gwp[m][i] = gr[i]; vwp[m][i] = vr[i]; }
  }

  __shared__ float xt[8][128];
  __shared__ float yt[8][128];

  for (int e0 = blockIdx.x * 8; e0 < E; e0 += stride) {
    const int e = e0 + slot;
    const bool act = (e < E);
    int dst = 0;

    if (act) {
      const int src = eidx[e];
      dst = eidx[E + e];
      uint2 p0 = *(const uint2*)(h0 + (size_t)src * WIDTH + 4 * q);
      uint2 p1 = *(const uint2*)(h1 + (size_t)dst * WIDTH + 4 * q);
      float xx[4];
      xx[0] = h2fl(p0.x) + h2fl(p1.x);
      xx[1] = h2fh(p0.x) + h2fh(p1.x);
      xx[2] = h2fl(p0.y) + h2fl(p1.y);
      xx[3] = h2fh(p0.y) + h2fh(p1.y);

      float s  = xx[0] + xx[1] + xx[2] + xx[3];
      float ss = xx[0]*xx[0] + xx[1]*xx[1] + xx[2]*xx[2] + xx[3]*xx[3];
      s  += __shfl_xor(s, 1, 64);  s  += __shfl_xor(s, 2, 64);
      ss += __shfl_xor(ss, 1, 64); ss += __shfl_xor(ss, 2, 64);
      const float mean = s * 0.0625f;
      const float var  = ss * 0.0625f - mean * mean;
      const float rs   = rsqrtf(var + 1e-5f);

      // EmbeddingBag mean, padding_idx=0 (emb[0] == 0, adds are safe)
      const int a0 = eattr[e*3+0], a1 = eattr[e*3+1], a2 = eattr[e*3+2];
      uint2 q0 = *(const uint2*)(emb + (size_t)a0 * WIDTH + 4 * q);
      uint2 q1 = *(const uint2*)(emb + (size_t)a1 * WIDTH + 4 * q);
      uint2 q2 = *(const uint2*)(emb + (size_t)a2 * WIDTH + 4 * q);
      const int cnt = (a0 != 0) + (a1 != 0) + (a2 != 0);
      const float inv = 1.f / (float)(cnt > 1 ? cnt : 1);

      float bg[4];
      bg[0] = (bfl(q0.x) + bfl(q1.x) + bfl(q2.x)) * inv;
      bg[1] = (bfh(q0.x) + bfh(q1.x) + bfh(q2.x)) * inv;
      bg[2] = (bfl(q0.y) + bfl(q1.y) + bfl(q2.y)) * inv;
      bg[3] = (bfh(q0.y) + bfh(q1.y) + bfh(q2.y)) * inv;

      float xn[4];
      #pragma unroll
      for (int m = 0; m < 4; ++m) xn[m] = (xx[m] - mean) * rs;
      *(float4*)&xt[slot][4 * q] = make_float4(xn[0], xn[1], xn[2], xn[3]);
      *(float4*)&yt[slot][4 * q] = make_float4(xn[0]+bg[0], xn[1]+bg[1], xn[2]+bg[2], xn[3]+bg[3]);
    }
    __syncthreads();

    if (act) {
      float ga[4] = {0.f, 0.f, 0.f, 0.f};
      float va[4] = {0.f, 0.f, 0.f, 0.f};
      #pragma unroll
      for (int ii = 0; ii < 4; ++ii) {
        float4 yv = *(const float4*)&yt[slot][g * 16 + ii * 4];
        float4 xv = *(const float4*)&xt[slot][g * 16 + ii * 4];
        #pragma unroll
        for (int m = 0; m < 4; ++m) {
          const u32 pg0 = gwp[m][ii*2], pg1 = gwp[m][ii*2+1];
          const u32 pv0 = vwp[m][ii*2], pv1 = vwp[m][ii*2+1];
          ga[m] = fmaf(bfl(pg0), yv.x, ga[m]);
          ga[m] = fmaf(bfh(pg0), yv.y, ga[m]);
          ga[m] = fmaf(bfl(pg1), yv.z, ga[m]);
          ga[m] = fmaf(bfh(pg1), yv.w, ga[m]);
          va[m] = fmaf(bfl(pv0), xv.x, va[m]);
          va[m] = fmaf(bfh(pv0), xv.y, va[m]);
          va[m] = fmaf(bfl(pv1), xv.z, va[m]);
          va[m] = fmaf(bfh(pv1), xv.w, va[m]);
        }
      }
      float* ap = agg + (size_t)dst * WIDTH + 4 * q;
      #pragma unroll
      for (int m = 0; m < 4; ++m) {
        const float r = fmaxf(ga[m], 0.f) * va[m];
        atomicAdd(ap + m, r);
      }
    }
    __syncthreads();
  }
}

// ---------------------------------------------------------------------------
// k_post: out = (agg @ pw^T + pb) * deg^degree_param ; out dtype per flag.
// ---------------------------------------------------------------------------
__global__ __launch_bounds__(128, 2) void k_post(
    const float* __restrict__ agg, const u16* __restrict__ pb16,
    void* __restrict__ out, const void* __restrict__ degsrc)
{
  const int c = threadIdx.x;
  const int node0 = blockIdx.x * 64;

  u32 wp[64];
  const u32* wrow = (const u32*)(pb16 + OFF_PW + (size_t)c * WIDTH);
  #pragma unroll
  for (int k2 = 0; k2 < 64; ++k2) wp[k2] = wrow[k2];
  const float bias = b2f(pb16[OFF_PB + c]);
  const float dpc  = b2f(pb16[OFF_DP + c]);
  const bool f32 = is_fp32(degsrc);

  for (int g = 0; g < 8; ++g) {
    const float2* arow = (const float2*)(agg + (size_t)(node0 + g * 8) * WIDTH);
    float acc[8];
    #pragma unroll
    for (int n = 0; n < 8; ++n) acc[n] = bias;
    #pragma unroll
    for (int k2 = 0; k2 < 64; ++k2) {
      const float wl = bfl(wp[k2]), wh = bfh(wp[k2]);
      #pragma unroll
      for (int n = 0; n < 8; ++n) {
        float2 av = arow[n * 64 + k2];               // block-uniform
        acc[n] = fmaf(av.x, wl, acc[n]);
        acc[n] = fmaf(av.y, wh, acc[n]);
      }
    }
    #pragma unroll
    for (int n = 0; n < 8; ++n) {
      const int node = node0 + g * 8 + n;
      const float d  = b2f(pb16[OFF_DEG + node]);    // deg >= 1
      const float sc = __expf(dpc * __logf(d));      // deg^dpc
      const float v  = acc[n] * sc;
      if (f32) ((float*)out)[(size_t)node * WIDTH + c] = v;
      else     ((u16*)out)[(size_t)node * WIDTH + c] = f2b(v);
    }
  }
}

extern "C" void kernel_launch(void* const* d_in, const int* in_sizes, int n_in,
                              void* d_out, int out_size, void* d_ws, size_t ws_size,
                              hipStream_t stream)
{
  (void)n_in; (void)out_size; (void)ws_size;
  const void* x     = d_in[0];
  const void* deg   = d_in[1];
  const int*  eidx  = (const int*)d_in[2];
  const int*  eattr = (const int*)d_in[3];

  const int N = in_sizes[1];            // 200000
  const int E = in_sizes[2] / 2;        // 1000000

  float* agg  = (float*)d_ws;
  u16*   h1   = (u16*)((char*)d_ws + (size_t)N * WIDTH * sizeof(float));
  u16*   pb16 = h1 + (size_t)N * WIDTH;
  u16*   h0   = (u16*)d_out;            // f16 scratch; fully overwritten by k_post

  const int total = OFF_DEG + N;
  k_convert<<<(total + 255) / 256, 256, 0, stream>>>(
      d_in[4], d_in[5], d_in[6], d_in[7], d_in[8], d_in[9], d_in[10],
      d_in[11], d_in[12], d_in[13], deg, pb16, total);

  const int nb = N / 64;                // 3125
  k_pre<<<nb, 256, 0, stream>>>(x, pb16, h0, h1, agg, deg);

  int egrid = (E + 7) / 8;
  if (egrid > 12500) egrid = 12500;     // grid-stride, 10 sweeps at E=1e6
  const int stride = egrid * 8;
  k_edge<<<egrid, 256, 0, stream>>>(h0, h1, eidx, eattr, pb16, agg, E, stride);

  k_post<<<nb, 128, 0, stream>>>(agg, pb16, d_out, deg);
}

// Round 3
// 2064.932 us; speedup vs baseline: 1.5975x; 1.5975x over previous
//
#include <hip/hip_runtime.h>
#include <hip/hip_bf16.h>
#include <hip/hip_fp16.h>

// MetaGIN round 3: MFMA node GEMMs (no LDS), barrier-free edge kernel with
// shfl-based grouped conv + precomputed gemb = gw@emb (bag folded in).
// Dtype-adaptive (fp32 vs bf16 dataset detected from deg bit pattern).
//
// ws layout: [ agg N*128 f32 | h1 N*128 f16 | pb16 arena | gemb 33*128 f32 ]
// h0 (N*128 f16) lives in d_out (fully overwritten by k_post at the end).

typedef unsigned short u16;
typedef unsigned int   u32;

#define WIDTH 128

// params_b16 element offsets (all bf16)
#define OFF_W0   0        // 16384
#define OFF_B0   16384    // 128
#define OFF_W1   16512    // 16384
#define OFF_B1   32896    // 128
#define OFF_EMB  33024    // 33*128 = 4224
#define OFF_GW   37248    // 128*16 = 2048
#define OFF_VW   39296    // 2048
#define OFF_PW   41344    // 16384
#define OFF_PB   57728    // 128
#define OFF_DP   57856    // 128
#define OFF_DEG  57984    // N
#define ARENA_PAD 258048  // u16 elems (>= OFF_DEG+N rounded up, even)

typedef __attribute__((ext_vector_type(8))) short bf16x8;
typedef __attribute__((ext_vector_type(4))) float f32x4;

__device__ __forceinline__ float bfl(u32 p){ return __uint_as_float(p << 16); }
__device__ __forceinline__ float bfh(u32 p){ return __uint_as_float(p & 0xffff0000u); }
__device__ __forceinline__ float b2f(u16 u){ return __uint_as_float(((u32)u) << 16); }
__device__ __forceinline__ u16   f2b(float f){
  u32 u = __float_as_uint(f);
  u += 0x7fffu + ((u >> 16) & 1u);   // RNE
  return (u16)(u >> 16);
}
__device__ __forceinline__ float h2fl(u32 p){ return __half2float(__ushort_as_half((u16)(p & 0xffffu))); }
__device__ __forceinline__ float h2fh(u32 p){ return __half2float(__ushort_as_half((u16)(p >> 16))); }
__device__ __forceinline__ u16   f2h(float f){ return __half_as_ushort(__float2half(f)); }

__device__ __forceinline__ bool is_fp32(const void* degsrc){
  // deg = exact ints 1..7: fp32 word0 low16 == 0; bf16 word0 low16 = bf16(deg0) != 0
  return ((*(const u32*)degsrc) & 0xffffu) == 0u;
}

__device__ __forceinline__ bf16x8 cvt8(float4 a, float4 b){
  bf16x8 r;
  r[0]=(short)f2b(a.x); r[1]=(short)f2b(a.y); r[2]=(short)f2b(a.z); r[3]=(short)f2b(a.w);
  r[4]=(short)f2b(b.x); r[5]=(short)f2b(b.y); r[6]=(short)f2b(b.z); r[7]=(short)f2b(b.w);
  return r;
}

// ---------------------------------------------------------------------------
// k_convert: normalize all small float params (+deg) into bf16 arena.
// ---------------------------------------------------------------------------
__device__ __forceinline__ u16 cvt_one(const void* src, int j, bool f32){
  return f32 ? f2b(((const float*)src)[j]) : ((const u16*)src)[j];
}

__global__ void k_convert(const void* w0, const void* b0, const void* w1, const void* b1,
                          const void* emb, const void* gw, const void* vw,
                          const void* pw, const void* pb, const void* dp,
                          const void* degsrc, u16* __restrict__ pb16, int total)
{
  const int i = blockIdx.x * 256 + threadIdx.x;
  if (i >= total) return;
  const bool f32 = is_fp32(degsrc);
  u16 v;
  if      (i < OFF_B0 ) v = cvt_one(w0,  i,           f32);
  else if (i < OFF_W1 ) v = cvt_one(b0,  i - OFF_B0,  f32);
  else if (i < OFF_B1 ) v = cvt_one(w1,  i - OFF_W1,  f32);
  else if (i < OFF_EMB) v = cvt_one(b1,  i - OFF_B1,  f32);
  else if (i < OFF_GW ) v = cvt_one(emb, i - OFF_EMB, f32);
  else if (i < OFF_VW ) v = cvt_one(gw,  i - OFF_GW,  f32);
  else if (i < OFF_PW ) v = cvt_one(vw,  i - OFF_VW,  f32);
  else if (i < OFF_PB ) v = cvt_one(pw,  i - OFF_PW,  f32);
  else if (i < OFF_DP ) v = cvt_one(pb,  i - OFF_PB,  f32);
  else if (i < OFF_DEG) v = cvt_one(dp,  i - OFF_DP,  f32);
  else                  v = cvt_one(degsrc, i - OFF_DEG, f32);
  pb16[i] = v;
}

__device__ __forceinline__ float read_f(const void* src, int j, bool f32){
  return f32 ? ((const float*)src)[j] : b2f(((const u16*)src)[j]);
}

// gemb[a][c] = sum_i gw[c][i] * emb[a][ (c/16)*16 + i ]   (f32, 33x128)
__global__ void k_gemb(const void* gwsrc, const void* embsrc, const void* degsrc,
                       float* __restrict__ gemb)
{
  const int tid = blockIdx.x * 256 + threadIdx.x;
  if (tid >= 33 * 128) return;
  const bool f32 = is_fp32(degsrc);
  const int a = tid >> 7, c = tid & 127, g = c >> 4;
  float s = 0.f;
  #pragma unroll
  for (int i = 0; i < 16; ++i)
    s += read_f(gwsrc, c * 16 + i, f32) * read_f(embsrc, a * WIDTH + g * 16 + i, f32);
  gemb[tid] = s;
}

// ---------------------------------------------------------------------------
// k_pre: h0 = x@w0^T + b0, h1 = x@w1^T + b1 via MFMA 16x16x32 bf16, f16 out.
// 4 waves: wave>>1 selects matrix, wave&1 selects 64-col half. 64 nodes/block.
// A frag: x[node0+mt*16+lid][ks*32+quad*8 ..+8]; B frag: w[c][k] same pattern.
// C layout: col=lane&15, row=quad*4+reg (measured, m89).
// ---------------------------------------------------------------------------
__global__ __launch_bounds__(256, 2) void k_pre(
    const void* __restrict__ x, const u16* __restrict__ pb16,
    u16* __restrict__ h0, u16* __restrict__ h1,
    float* __restrict__ agg, const void* __restrict__ degsrc)
{
  const int t = threadIdx.x;
  const int lane = t & 63, lid = lane & 15, quad = lane >> 4;
  const int w = t >> 6, mat = w >> 1, c0 = (w & 1) * 64;
  const int node0 = blockIdx.x * 64;

  // zero agg rows for this block's 64 nodes
  {
    float4 z = make_float4(0.f, 0.f, 0.f, 0.f);
    float4* ar = (float4*)(agg + (size_t)node0 * WIDTH);
    #pragma unroll
    for (int i = 0; i < 8; ++i) ar[t + 256 * i] = z;
  }

  const u16* wm = pb16 + (mat ? OFF_W1 : OFF_W0);
  const u16* bs = pb16 + (mat ? OFF_B1 : OFF_B0);
  u16* hout = mat ? h1 : h0;
  const bool f32 = is_fp32(degsrc);

  f32x4 acc[4][4];
  #pragma unroll
  for (int nt = 0; nt < 4; ++nt) {
    const float bias = b2f(bs[c0 + nt * 16 + lid]);
    #pragma unroll
    for (int mt = 0; mt < 4; ++mt)
      #pragma unroll
      for (int r = 0; r < 4; ++r) acc[mt][nt][r] = bias;
  }

  #pragma unroll
  for (int ks = 0; ks < 4; ++ks) {
    bf16x8 a[4], b[4];
    #pragma unroll
    for (int nt = 0; nt < 4; ++nt)
      b[nt] = *(const bf16x8*)(wm + (size_t)(c0 + nt * 16 + lid) * WIDTH + ks * 32 + quad * 8);
    if (f32) {
      #pragma unroll
      for (int mt = 0; mt < 4; ++mt) {
        const float4* xr = (const float4*)((const float*)x +
            (size_t)(node0 + mt * 16 + lid) * WIDTH + ks * 32 + quad * 8);
        a[mt] = cvt8(xr[0], xr[1]);
      }
    } else {
      #pragma unroll
      for (int mt = 0; mt < 4; ++mt)
        a[mt] = *(const bf16x8*)((const u16*)x +
            (size_t)(node0 + mt * 16 + lid) * WIDTH + ks * 32 + quad * 8);
    }
    #pragma unroll
    for (int mt = 0; mt < 4; ++mt)
      #pragma unroll
      for (int nt = 0; nt < 4; ++nt)
        acc[mt][nt] = __builtin_amdgcn_mfma_f32_16x16x32_bf16(a[mt], b[nt], acc[mt][nt], 0, 0, 0);
  }

  #pragma unroll
  for (int mt = 0; mt < 4; ++mt)
    #pragma unroll
    for (int nt = 0; nt < 4; ++nt)
      #pragma unroll
      for (int r = 0; r < 4; ++r)
        hout[(size_t)(node0 + mt * 16 + quad * 4 + r) * WIDTH + c0 + nt * 16 + lid] =
            f2h(acc[mt][nt][r]);
}

// ---------------------------------------------------------------------------
// k_edge: barrier-free. 32 lanes/edge, 4 ch/lane. GroupNorm + conv transpose
// via shfl_xor in 4-lane clusters. bag folded: gate = relu(gw@xn + sum gemb/cnt).
// ---------------------------------------------------------------------------
__global__ __launch_bounds__(256, 2) void k_edge(
    const u16* __restrict__ h0, const u16* __restrict__ h1,
    const int* __restrict__ eidx, const int* __restrict__ eattr,
    const u16* __restrict__ pb16, const float* __restrict__ gemb,
    float* __restrict__ agg, const int E, const int stride)
{
  const int t    = threadIdx.x;
  const int slot = t >> 5;        // 8 edges per block
  const int q    = t & 31;        // lane within edge; channels 4q..4q+3

  u32 gwp[4][8], vwp[4][8];       // rows 4q+m (16 bf16 each)
  #pragma unroll
  for (int m = 0; m < 4; ++m) {
    const u32* gr = (const u32*)(pb16 + OFF_GW + (size_t)(4 * q + m) * 16);
    const u32* vr = (const u32*)(pb16 + OFF_VW + (size_t)(4 * q + m) * 16);
    #pragma unroll
    for (int i = 0; i < 8; ++i) { gwp[m][i] = gr[i]; vwp[m][i] = vr[i]; }
  }

  for (int e0 = blockIdx.x * 8 + slot; e0 < E; e0 += stride) {
    const int e = e0;
    const int src = eidx[e];
    const int dst = eidx[E + e];

    uint2 p0 = *(const uint2*)(h0 + (size_t)src * WIDTH + 4 * q);
    uint2 p1 = *(const uint2*)(h1 + (size_t)dst * WIDTH + 4 * q);
    float xx[4];
    xx[0] = h2fl(p0.x) + h2fl(p1.x);
    xx[1] = h2fh(p0.x) + h2fh(p1.x);
    xx[2] = h2fl(p0.y) + h2fl(p1.y);
    xx[3] = h2fh(p0.y) + h2fh(p1.y);

    float s  = xx[0] + xx[1] + xx[2] + xx[3];
    float ss = xx[0]*xx[0] + xx[1]*xx[1] + xx[2]*xx[2] + xx[3]*xx[3];
    s  += __shfl_xor(s, 1, 64);  s  += __shfl_xor(s, 2, 64);
    ss += __shfl_xor(ss, 1, 64); ss += __shfl_xor(ss, 2, 64);
    const float mean = s * 0.0625f;
    const float var  = ss * 0.0625f - mean * mean;
    const float rs   = rsqrtf(var + 1e-5f);
    float xn[4];
    #pragma unroll
    for (int m = 0; m < 4; ++m) xn[m] = (xx[m] - mean) * rs;

    // folded bag: gb = (gemb[a0]+gemb[a1]+gemb[a2])[4q..4q+3] / cnt
    const int a0 = eattr[e*3+0], a1 = eattr[e*3+1], a2 = eattr[e*3+2];
    float4 g0 = *(const float4*)(gemb + (size_t)a0 * WIDTH + 4 * q);
    float4 g1 = *(const float4*)(gemb + (size_t)a1 * WIDTH + 4 * q);
    float4 g2 = *(const float4*)(gemb + (size_t)a2 * WIDTH + 4 * q);
    const int cnt = (a0 != 0) + (a1 != 0) + (a2 != 0);
    const float inv = 1.f / (float)(cnt > 1 ? cnt : 1);

    float ga[4], va[4];
    ga[0] = (g0.x + g1.x + g2.x) * inv;
    ga[1] = (g0.y + g1.y + g2.y) * inv;
    ga[2] = (g0.z + g1.z + g2.z) * inv;
    ga[3] = (g0.w + g1.w + g2.w) * inv;
    va[0] = va[1] = va[2] = va[3] = 0.f;

    #pragma unroll
    for (int delta = 0; delta < 4; ++delta) {
      float xd[4];
      if (delta == 0) {
        xd[0]=xn[0]; xd[1]=xn[1]; xd[2]=xn[2]; xd[3]=xn[3];
      } else {
        #pragma unroll
        for (int j = 0; j < 4; ++j) xd[j] = __shfl_xor(xn[j], delta, 64);
      }
      const int b2 = ((q ^ delta) & 3) * 2;   // u32 index of 4-ch slice
      #pragma unroll
      for (int m = 0; m < 4; ++m) {
        const u32 gA = gwp[m][b2], gB = gwp[m][b2+1];
        const u32 vA = vwp[m][b2], vB = vwp[m][b2+1];
        ga[m] = fmaf(bfl(gA), xd[0], ga[m]);
        ga[m] = fmaf(bfh(gA), xd[1], ga[m]);
        ga[m] = fmaf(bfl(gB), xd[2], ga[m]);
        ga[m] = fmaf(bfh(gB), xd[3], ga[m]);
        va[m] = fmaf(bfl(vA), xd[0], va[m]);
        va[m] = fmaf(bfh(vA), xd[1], va[m]);
        va[m] = fmaf(bfl(vB), xd[2], va[m]);
        va[m] = fmaf(bfh(vB), xd[3], va[m]);
      }
    }

    float* ap = agg + (size_t)dst * WIDTH + 4 * q;
    #pragma unroll
    for (int m = 0; m < 4; ++m)
      atomicAdd(ap + m, fmaxf(ga[m], 0.f) * va[m]);
  }
}

// ---------------------------------------------------------------------------
// k_post: out = (agg @ pw^T + pb) * deg^dp via MFMA. 4 waves: wave&1 -> col
// half, wave>>1 -> 32-node half. agg f32 converted to bf16 frags inline.
// ---------------------------------------------------------------------------
__global__ __launch_bounds__(256, 2) void k_post(
    const float* __restrict__ agg, const u16* __restrict__ pb16,
    void* __restrict__ out, const void* __restrict__ degsrc)
{
  const int t = threadIdx.x;
  const int lane = t & 63, lid = lane & 15, quad = lane >> 4;
  const int w = t >> 6, c0 = (w & 1) * 64, mh = (w >> 1) * 32;
  const int node0 = blockIdx.x * 64;
  const bool f32o = is_fp32(degsrc);

  f32x4 acc[2][4];
  float dpc[4];
  #pragma unroll
  for (int nt = 0; nt < 4; ++nt) {
    const float bias = b2f(pb16[OFF_PB + c0 + nt * 16 + lid]);
    dpc[nt] = b2f(pb16[OFF_DP + c0 + nt * 16 + lid]);
    #pragma unroll
    for (int mt = 0; mt < 2; ++mt)
      #pragma unroll
      for (int r = 0; r < 4; ++r) acc[mt][nt][r] = bias;
  }

  #pragma unroll
  for (int ks = 0; ks < 4; ++ks) {
    bf16x8 a[2], b[4];
    #pragma unroll
    for (int nt = 0; nt < 4; ++nt)
      b[nt] = *(const bf16x8*)(pb16 + OFF_PW + (size_t)(c0 + nt * 16 + lid) * WIDTH + ks * 32 + quad * 8);
    #pragma unroll
    for (int mt = 0; mt < 2; ++mt) {
      const float4* ar = (const float4*)(agg +
          (size_t)(node0 + mh + mt * 16 + lid) * WIDTH + ks * 32 + quad * 8);
      a[mt] = cvt8(ar[0], ar[1]);
    }
    #pragma unroll
    for (int mt = 0; mt < 2; ++mt)
      #pragma unroll
      for (int nt = 0; nt < 4; ++nt)
        acc[mt][nt] = __builtin_amdgcn_mfma_f32_16x16x32_bf16(a[mt], b[nt], acc[mt][nt], 0, 0, 0);
  }

  float logd[2][4];
  #pragma unroll
  for (int mt = 0; mt < 2; ++mt)
    #pragma unroll
    for (int r = 0; r < 4; ++r)
      logd[mt][r] = __logf(b2f(pb16[OFF_DEG + node0 + mh + mt * 16 + quad * 4 + r]));

  #pragma unroll
  for (int mt = 0; mt < 2; ++mt)
    #pragma unroll
    for (int nt = 0; nt < 4; ++nt)
      #pragma unroll
      for (int r = 0; r < 4; ++r) {
        const int node = node0 + mh + mt * 16 + quad * 4 + r;
        const float v = acc[mt][nt][r] * __expf(dpc[nt] * logd[mt][r]);
        if (f32o) ((float*)out)[(size_t)node * WIDTH + c0 + nt * 16 + lid] = v;
        else      ((u16*)out)[(size_t)node * WIDTH + c0 + nt * 16 + lid] = f2b(v);
      }
}

extern "C" void kernel_launch(void* const* d_in, const int* in_sizes, int n_in,
                              void* d_out, int out_size, void* d_ws, size_t ws_size,
                              hipStream_t stream)
{
  (void)n_in; (void)out_size; (void)ws_size;
  const void* x     = d_in[0];
  const void* deg   = d_in[1];
  const int*  eidx  = (const int*)d_in[2];
  const int*  eattr = (const int*)d_in[3];

  const int N = in_sizes[1];            // 200000
  const int E = in_sizes[2] / 2;        // 1000000

  float* agg  = (float*)d_ws;
  u16*   h1   = (u16*)((char*)d_ws + (size_t)N * WIDTH * sizeof(float));
  u16*   pb16 = h1 + (size_t)N * WIDTH;
  float* gemb = (float*)(pb16 + ARENA_PAD);
  u16*   h0   = (u16*)d_out;            // f16 scratch; overwritten by k_post

  const int total = OFF_DEG + N;
  k_convert<<<(total + 255) / 256, 256, 0, stream>>>(
      d_in[4], d_in[5], d_in[6], d_in[7], d_in[8], d_in[9], d_in[10],
      d_in[11], d_in[12], d_in[13], deg, pb16, total);
  k_gemb<<<(33 * 128 + 255) / 256, 256, 0, stream>>>(d_in[9], d_in[8], deg, gemb);

  const int nb = N / 64;                // 3125
  k_pre<<<nb, 256, 0, stream>>>(x, pb16, h0, h1, agg, deg);

  const int egrid = 31250;              // 8 edges/block, 4 iterations
  const int stride = egrid * 8;
  k_edge<<<egrid, 256, 0, stream>>>(h0, h1, eidx, eattr, pb16, gemb, agg, E, stride);

  k_post<<<nb, 256, 0, stream>>>(agg, pb16, d_out, deg);
}

// Round 4
// 933.596 us; speedup vs baseline: 3.5334x; 2.2118x over previous
//
#include <hip/hip_runtime.h>
#include <hip/hip_bf16.h>
#include <hip/hip_fp16.h>

// MetaGIN round 4: CSR aggregation — counting-sort edges by dst, one wave per
// dst node, register accumulation, plain stores. No f32 atomics on agg.
// MFMA node GEMMs unchanged from R3. Dtype-adaptive (fp32 vs bf16 dataset).
//
// ws layout: agg N*128 f32 | h1 N*128 f16 | pb16 arena | gemb 33*128 f32 |
//            cnt N i32 | off N i32 | bsum 1024 i32 | ssrc E u32 | sattr E u32
// h0 (N*128 f16) lives in d_out (fully overwritten by k_post at the end).

typedef unsigned short u16;
typedef unsigned int   u32;

#define WIDTH 128

// params_b16 element offsets (all bf16)
#define OFF_W0   0        // 16384
#define OFF_B0   16384    // 128
#define OFF_W1   16512    // 16384
#define OFF_B1   32896    // 128
#define OFF_EMB  33024    // 33*128 = 4224
#define OFF_GW   37248    // 128*16 = 2048
#define OFF_VW   39296    // 2048
#define OFF_PW   41344    // 16384
#define OFF_PB   57728    // 128
#define OFF_DP   57856    // 128
#define OFF_DEG  57984    // N
#define ARENA_PAD 258048  // u16 elems (>= OFF_DEG+N, even)

typedef __attribute__((ext_vector_type(8))) short bf16x8;
typedef __attribute__((ext_vector_type(4))) float f32x4;

__device__ __forceinline__ float bfl(u32 p){ return __uint_as_float(p << 16); }
__device__ __forceinline__ float bfh(u32 p){ return __uint_as_float(p & 0xffff0000u); }
__device__ __forceinline__ float b2f(u16 u){ return __uint_as_float(((u32)u) << 16); }
__device__ __forceinline__ u16   f2b(float f){
  u32 u = __float_as_uint(f);
  u += 0x7fffu + ((u >> 16) & 1u);   // RNE
  return (u16)(u >> 16);
}
__device__ __forceinline__ float h2fl(u32 p){ return __half2float(__ushort_as_half((u16)(p & 0xffffu))); }
__device__ __forceinline__ float h2fh(u32 p){ return __half2float(__ushort_as_half((u16)(p >> 16))); }
__device__ __forceinline__ u16   f2h(float f){ return __half_as_ushort(__float2half(f)); }

__device__ __forceinline__ bool is_fp32(const void* degsrc){
  // deg = exact ints 1..7: fp32 word0 low16 == 0; bf16 word0 low16 != 0
  return ((*(const u32*)degsrc) & 0xffffu) == 0u;
}

__device__ __forceinline__ bf16x8 cvt8(float4 a, float4 b){
  bf16x8 r;
  r[0]=(short)f2b(a.x); r[1]=(short)f2b(a.y); r[2]=(short)f2b(a.z); r[3]=(short)f2b(a.w);
  r[4]=(short)f2b(b.x); r[5]=(short)f2b(b.y); r[6]=(short)f2b(b.z); r[7]=(short)f2b(b.w);
  return r;
}

// ---------------------------------------------------------------------------
// k_convert: normalize all small float params (+deg) into bf16 arena.
// ---------------------------------------------------------------------------
__device__ __forceinline__ u16 cvt_one(const void* src, int j, bool f32){
  return f32 ? f2b(((const float*)src)[j]) : ((const u16*)src)[j];
}

__global__ void k_convert(const void* w0, const void* b0, const void* w1, const void* b1,
                          const void* emb, const void* gw, const void* vw,
                          const void* pw, const void* pb, const void* dp,
                          const void* degsrc, u16* __restrict__ pb16, int total)
{
  const int i = blockIdx.x * 256 + threadIdx.x;
  if (i >= total) return;
  const bool f32 = is_fp32(degsrc);
  u16 v;
  if      (i < OFF_B0 ) v = cvt_one(w0,  i,           f32);
  else if (i < OFF_W1 ) v = cvt_one(b0,  i - OFF_B0,  f32);
  else if (i < OFF_B1 ) v = cvt_one(w1,  i - OFF_W1,  f32);
  else if (i < OFF_EMB) v = cvt_one(b1,  i - OFF_B1,  f32);
  else if (i < OFF_GW ) v = cvt_one(emb, i - OFF_EMB, f32);
  else if (i < OFF_VW ) v = cvt_one(gw,  i - OFF_GW,  f32);
  else if (i < OFF_PW ) v = cvt_one(vw,  i - OFF_VW,  f32);
  else if (i < OFF_PB ) v = cvt_one(pw,  i - OFF_PW,  f32);
  else if (i < OFF_DP ) v = cvt_one(pb,  i - OFF_PB,  f32);
  else if (i < OFF_DEG) v = cvt_one(dp,  i - OFF_DP,  f32);
  else                  v = cvt_one(degsrc, i - OFF_DEG, f32);
  pb16[i] = v;
}

__device__ __forceinline__ float read_f(const void* src, int j, bool f32){
  return f32 ? ((const float*)src)[j] : b2f(((const u16*)src)[j]);
}

// gemb[a][c] = sum_i gw[c][i] * emb[a][(c/16)*16 + i]   (f32, 33x128)
__global__ void k_gemb(const void* gwsrc, const void* embsrc, const void* degsrc,
                       float* __restrict__ gemb)
{
  const int tid = blockIdx.x * 256 + threadIdx.x;
  if (tid >= 33 * 128) return;
  const bool f32 = is_fp32(degsrc);
  const int a = tid >> 7, c = tid & 127, g = c >> 4;
  float s = 0.f;
  #pragma unroll
  for (int i = 0; i < 16; ++i)
    s += read_f(gwsrc, c * 16 + i, f32) * read_f(embsrc, a * WIDTH + g * 16 + i, f32);
  gemb[tid] = s;
}

// ---------------------------------------------------------------------------
// counting-sort chain: zero -> hist -> scan1 -> scan2 -> scan3 -> scatter
// ---------------------------------------------------------------------------
__global__ void k_zero(int* __restrict__ cnt, int n){
  const int i = blockIdx.x * 256 + threadIdx.x;
  if (i < n) cnt[i] = 0;
}

__global__ void k_hist(const int* __restrict__ eidx, int* __restrict__ cnt, int E){
  const int e = blockIdx.x * 256 + threadIdx.x;
  if (e < E) atomicAdd(&cnt[eidx[E + e]], 1);
}

// block sums over 1024-elem chunks
__global__ void k_scan1(const int* __restrict__ cnt, int* __restrict__ bsum, int n){
  const int t = threadIdx.x, b = blockIdx.x;
  const int i0 = b * 1024 + t * 4;
  int s = 0;
  #pragma unroll
  for (int j = 0; j < 4; ++j) { int i = i0 + j; if (i < n) s += cnt[i]; }
  __shared__ int sb[256];
  sb[t] = s; __syncthreads();
  for (int d = 128; d > 0; d >>= 1) { if (t < d) sb[t] += sb[t + d]; __syncthreads(); }
  if (t == 0) bsum[b] = sb[0];
}

// single-block exclusive scan of bsum[0..nblk), nblk <= 1024
__global__ void k_scan2(int* __restrict__ bsum, int nblk){
  const int t = threadIdx.x;
  int v[4];
  const int i0 = t * 4;
  #pragma unroll
  for (int j = 0; j < 4; ++j) { int i = i0 + j; v[j] = (i < nblk) ? bsum[i] : 0; }
  int tsum = v[0] + v[1] + v[2] + v[3];
  __shared__ int sb[256];
  sb[t] = tsum; __syncthreads();
  for (int d = 1; d < 256; d <<= 1) {
    int x = (t >= d) ? sb[t - d] : 0;
    __syncthreads();
    sb[t] += x;
    __syncthreads();
  }
  int run = sb[t] - tsum;            // exclusive prefix of this thread
  #pragma unroll
  for (int j = 0; j < 4; ++j) { int nv = run; run += v[j]; v[j] = nv; }
  #pragma unroll
  for (int j = 0; j < 4; ++j) { int i = i0 + j; if (i < nblk) bsum[i] = v[j]; }
}

// full exclusive scan: off[i] = bsum[b] + local exclusive prefix
__global__ void k_scan3(const int* __restrict__ cnt, const int* __restrict__ bsum,
                        int* __restrict__ off, int n){
  const int t = threadIdx.x, b = blockIdx.x;
  const int i0 = b * 1024 + t * 4;
  int c[4];
  #pragma unroll
  for (int j = 0; j < 4; ++j) { int i = i0 + j; c[j] = (i < n) ? cnt[i] : 0; }
  int tsum = c[0] + c[1] + c[2] + c[3];
  __shared__ int sb[256];
  sb[t] = tsum; __syncthreads();
  for (int d = 1; d < 256; d <<= 1) {
    int x = (t >= d) ? sb[t - d] : 0;
    __syncthreads();
    sb[t] += x;
    __syncthreads();
  }
  int run = bsum[b] + sb[t] - tsum;
  #pragma unroll
  for (int j = 0; j < 4; ++j) {
    int i = i0 + j;
    if (i < n) off[i] = run;
    run += c[j];
  }
}

// scatter edges into dst-sorted order; off[dst] becomes END pointer after this
__global__ void k_scatter(const int* __restrict__ eidx, const int* __restrict__ eattr,
                          int* __restrict__ off, u32* __restrict__ ssrc,
                          u32* __restrict__ sattr, int E){
  const int e = blockIdx.x * 256 + threadIdx.x;
  if (e >= E) return;
  const int dst = eidx[E + e];
  const int pos = atomicAdd(&off[dst], 1);
  ssrc[pos] = (u32)eidx[e];
  const u32 a0 = (u32)eattr[e*3+0], a1 = (u32)eattr[e*3+1], a2 = (u32)eattr[e*3+2];
  sattr[pos] = a0 | (a1 << 6) | (a2 << 12);
}

// ---------------------------------------------------------------------------
// k_pre: h0 = x@w0^T + b0, h1 = x@w1^T + b1 via MFMA 16x16x32 bf16, f16 out.
// ---------------------------------------------------------------------------
__global__ __launch_bounds__(256, 2) void k_pre(
    const void* __restrict__ x, const u16* __restrict__ pb16,
    u16* __restrict__ h0, u16* __restrict__ h1, const void* __restrict__ degsrc)
{
  const int t = threadIdx.x;
  const int lane = t & 63, lid = lane & 15, quad = lane >> 4;
  const int w = t >> 6, mat = w >> 1, c0 = (w & 1) * 64;
  const int node0 = blockIdx.x * 64;

  const u16* wm = pb16 + (mat ? OFF_W1 : OFF_W0);
  const u16* bs = pb16 + (mat ? OFF_B1 : OFF_B0);
  u16* hout = mat ? h1 : h0;
  const bool f32 = is_fp32(degsrc);

  f32x4 acc[4][4];
  #pragma unroll
  for (int nt = 0; nt < 4; ++nt) {
    const float bias = b2f(bs[c0 + nt * 16 + lid]);
    #pragma unroll
    for (int mt = 0; mt < 4; ++mt)
      #pragma unroll
      for (int r = 0; r < 4; ++r) acc[mt][nt][r] = bias;
  }

  #pragma unroll
  for (int ks = 0; ks < 4; ++ks) {
    bf16x8 a[4], b[4];
    #pragma unroll
    for (int nt = 0; nt < 4; ++nt)
      b[nt] = *(const bf16x8*)(wm + (size_t)(c0 + nt * 16 + lid) * WIDTH + ks * 32 + quad * 8);
    if (f32) {
      #pragma unroll
      for (int mt = 0; mt < 4; ++mt) {
        const float4* xr = (const float4*)((const float*)x +
            (size_t)(node0 + mt * 16 + lid) * WIDTH + ks * 32 + quad * 8);
        a[mt] = cvt8(xr[0], xr[1]);
      }
    } else {
      #pragma unroll
      for (int mt = 0; mt < 4; ++mt)
        a[mt] = *(const bf16x8*)((const u16*)x +
            (size_t)(node0 + mt * 16 + lid) * WIDTH + ks * 32 + quad * 8);
    }
    #pragma unroll
    for (int mt = 0; mt < 4; ++mt)
      #pragma unroll
      for (int nt = 0; nt < 4; ++nt)
        acc[mt][nt] = __builtin_amdgcn_mfma_f32_16x16x32_bf16(a[mt], b[nt], acc[mt][nt], 0, 0, 0);
  }

  #pragma unroll
  for (int mt = 0; mt < 4; ++mt)
    #pragma unroll
    for (int nt = 0; nt < 4; ++nt)
      #pragma unroll
      for (int r = 0; r < 4; ++r)
        hout[(size_t)(node0 + mt * 16 + quad * 4 + r) * WIDTH + c0 + nt * 16 + lid] =
            f2h(acc[mt][nt][r]);
}

// ---------------------------------------------------------------------------
// k_agg: one wave per dst node. Lane q owns channels {2q, 2q+1}; 8-lane
// clusters = one 16-ch head. h1[dst] register-resident; per edge gather
// h0[src], GroupNorm + grouped conv via shfl_xor, accumulate relu(g)*v in
// registers, one plain float2 store to agg[dst].
// ---------------------------------------------------------------------------
__global__ __launch_bounds__(256, 4) void k_agg(
    const u16* __restrict__ h0, const u16* __restrict__ h1,
    const u32* __restrict__ ssrc, const u32* __restrict__ sattr,
    const int* __restrict__ off, const u16* __restrict__ pb16,
    const float* __restrict__ gemb, float* __restrict__ agg, const int N)
{
  const int dst = (blockIdx.x * 256 + threadIdx.x) >> 6;   // one wave per dst
  if (dst >= N) return;
  const int q = threadIdx.x & 63;
  const int p = q & 7;            // position within 8-lane head cluster
  const int c0 = 2 * q;           // my channels: c0, c0+1

  u32 gwp[2][8], vwp[2][8];       // conv rows c0, c0+1 (16 bf16 each)
  #pragma unroll
  for (int m = 0; m < 2; ++m) {
    const u32* gr = (const u32*)(pb16 + OFF_GW + (size_t)(c0 + m) * 16);
    const u32* vr = (const u32*)(pb16 + OFF_VW + (size_t)(c0 + m) * 16);
    #pragma unroll
    for (int i = 0; i < 8; ++i) { gwp[m][i] = gr[i]; vwp[m][i] = vr[i]; }
  }

  const u32 h1p = *(const u32*)(h1 + (size_t)dst * WIDTH + c0);
  const float h10 = h2fl(h1p), h11 = h2fh(h1p);

  const int n0 = dst ? off[dst - 1] : 0;   // off[] holds end pointers post-scatter
  const int n1 = off[dst];

  float acc0 = 0.f, acc1 = 0.f;
  for (int i = n0; i < n1; ++i) {
    const u32 src = ssrc[i];
    const u32 apw = sattr[i];
    const u32 hp = *(const u32*)(h0 + (size_t)src * WIDTH + c0);
    const float x0 = h2fl(hp) + h10;
    const float x1 = h2fh(hp) + h11;

    float s  = x0 + x1;
    float ss = x0 * x0 + x1 * x1;
    s  += __shfl_xor(s, 1, 64);  s  += __shfl_xor(s, 2, 64);  s  += __shfl_xor(s, 4, 64);
    ss += __shfl_xor(ss, 1, 64); ss += __shfl_xor(ss, 2, 64); ss += __shfl_xor(ss, 4, 64);
    const float mean = s * 0.0625f;
    const float var  = ss * 0.0625f - mean * mean;
    const float rs   = rsqrtf(var + 1e-5f);
    const float xn0 = (x0 - mean) * rs;
    const float xn1 = (x1 - mean) * rs;

    const int a0 = apw & 63, a1 = (apw >> 6) & 63, a2 = (apw >> 12) & 63;
    const float2 g0 = *(const float2*)(gemb + (size_t)a0 * WIDTH + c0);
    const float2 g1 = *(const float2*)(gemb + (size_t)a1 * WIDTH + c0);
    const float2 g2 = *(const float2*)(gemb + (size_t)a2 * WIDTH + c0);
    const int cb = (a0 != 0) + (a1 != 0) + (a2 != 0);
    const float inv = 1.f / (float)(cb > 1 ? cb : 1);

    float ga0 = (g0.x + g1.x + g2.x) * inv;
    float ga1 = (g0.y + g1.y + g2.y) * inv;
    float va0 = 0.f, va1 = 0.f;

    #pragma unroll
    for (int delta = 0; delta < 8; ++delta) {
      const float xd0 = delta ? __shfl_xor(xn0, delta, 64) : xn0;
      const float xd1 = delta ? __shfl_xor(xn1, delta, 64) : xn1;
      const int jj = p ^ delta;
      const u32 wg0 = gwp[0][jj], wg1 = gwp[1][jj];
      const u32 wv0 = vwp[0][jj], wv1 = vwp[1][jj];
      ga0 = fmaf(bfl(wg0), xd0, ga0); ga0 = fmaf(bfh(wg0), xd1, ga0);
      ga1 = fmaf(bfl(wg1), xd0, ga1); ga1 = fmaf(bfh(wg1), xd1, ga1);
      va0 = fmaf(bfl(wv0), xd0, va0); va0 = fmaf(bfh(wv0), xd1, va0);
      va1 = fmaf(bfl(wv1), xd0, va1); va1 = fmaf(bfh(wv1), xd1, va1);
    }
    acc0 += fmaxf(ga0, 0.f) * va0;
    acc1 += fmaxf(ga1, 0.f) * va1;
  }
  *(float2*)(agg + (size_t)dst * WIDTH + c0) = make_float2(acc0, acc1);
}

// ---------------------------------------------------------------------------
// k_post: out = (agg @ pw^T + pb) * deg^dp via MFMA.
// ---------------------------------------------------------------------------
__global__ __launch_bounds__(256, 2) void k_post(
    const float* __restrict__ agg, const u16* __restrict__ pb16,
    void* __restrict__ out, const void* __restrict__ degsrc)
{
  const int t = threadIdx.x;
  const int lane = t & 63, lid = lane & 15, quad = lane >> 4;
  const int w = t >> 6, c0 = (w & 1) * 64, mh = (w >> 1) * 32;
  const int node0 = blockIdx.x * 64;
  const bool f32o = is_fp32(degsrc);

  f32x4 acc[2][4];
  float dpc[4];
  #pragma unroll
  for (int nt = 0; nt < 4; ++nt) {
    const float bias = b2f(pb16[OFF_PB + c0 + nt * 16 + lid]);
    dpc[nt] = b2f(pb16[OFF_DP + c0 + nt * 16 + lid]);
    #pragma unroll
    for (int mt = 0; mt < 2; ++mt)
      #pragma unroll
      for (int r = 0; r < 4; ++r) acc[mt][nt][r] = bias;
  }

  #pragma unroll
  for (int ks = 0; ks < 4; ++ks) {
    bf16x8 a[2], b[4];
    #pragma unroll
    for (int nt = 0; nt < 4; ++nt)
      b[nt] = *(const bf16x8*)(pb16 + OFF_PW + (size_t)(c0 + nt * 16 + lid) * WIDTH + ks * 32 + quad * 8);
    #pragma unroll
    for (int mt = 0; mt < 2; ++mt) {
      const float4* ar = (const float4*)(agg +
          (size_t)(node0 + mh + mt * 16 + lid) * WIDTH + ks * 32 + quad * 8);
      a[mt] = cvt8(ar[0], ar[1]);
    }
    #pragma unroll
    for (int mt = 0; mt < 2; ++mt)
      #pragma unroll
      for (int nt = 0; nt < 4; ++nt)
        acc[mt][nt] = __builtin_amdgcn_mfma_f32_16x16x32_bf16(a[mt], b[nt], acc[mt][nt], 0, 0, 0);
  }

  float logd[2][4];
  #pragma unroll
  for (int mt = 0; mt < 2; ++mt)
    #pragma unroll
    for (int r = 0; r < 4; ++r)
      logd[mt][r] = __logf(b2f(pb16[OFF_DEG + node0 + mh + mt * 16 + quad * 4 + r]));

  #pragma unroll
  for (int mt = 0; mt < 2; ++mt)
    #pragma unroll
    for (int nt = 0; nt < 4; ++nt)
      #pragma unroll
      for (int r = 0; r < 4; ++r) {
        const int node = node0 + mh + mt * 16 + quad * 4 + r;
        const float v = acc[mt][nt][r] * __expf(dpc[nt] * logd[mt][r]);
        if (f32o) ((float*)out)[(size_t)node * WIDTH + c0 + nt * 16 + lid] = v;
        else      ((u16*)out)[(size_t)node * WIDTH + c0 + nt * 16 + lid] = f2b(v);
      }
}

extern "C" void kernel_launch(void* const* d_in, const int* in_sizes, int n_in,
                              void* d_out, int out_size, void* d_ws, size_t ws_size,
                              hipStream_t stream)
{
  (void)n_in; (void)out_size; (void)ws_size;
  const void* x     = d_in[0];
  const void* deg   = d_in[1];
  const int*  eidx  = (const int*)d_in[2];
  const int*  eattr = (const int*)d_in[3];

  const int N = in_sizes[1];            // 200000
  const int E = in_sizes[2] / 2;        // 1000000

  float* agg  = (float*)d_ws;
  u16*   h1   = (u16*)(agg + (size_t)N * WIDTH);
  u16*   pb16 = h1 + (size_t)N * WIDTH;
  float* gemb = (float*)(pb16 + ARENA_PAD);
  int*   cnt  = (int*)(gemb + 33 * WIDTH);
  int*   off  = cnt + N;
  int*   bsum = off + N;
  u32*   ssrc = (u32*)(bsum + 1024);
  u32*   sattr= ssrc + E;
  u16*   h0   = (u16*)d_out;            // f16 scratch; overwritten by k_post

  const int total = OFF_DEG + N;
  k_convert<<<(total + 255) / 256, 256, 0, stream>>>(
      d_in[4], d_in[5], d_in[6], d_in[7], d_in[8], d_in[9], d_in[10],
      d_in[11], d_in[12], d_in[13], deg, pb16, total);
  k_gemb<<<(33 * 128 + 255) / 256, 256, 0, stream>>>(d_in[9], d_in[8], deg, gemb);

  const int nb = N / 64;                // 3125
  k_pre<<<nb, 256, 0, stream>>>(x, pb16, h0, h1, deg);

  const int nblk = (N + 1023) / 1024;   // 196
  k_zero   <<<(N + 255) / 256, 256, 0, stream>>>(cnt, N);
  k_hist   <<<(E + 255) / 256, 256, 0, stream>>>(eidx, cnt, E);
  k_scan1  <<<nblk, 256, 0, stream>>>(cnt, bsum, N);
  k_scan2  <<<1, 256, 0, stream>>>(bsum, nblk);
  k_scan3  <<<nblk, 256, 0, stream>>>(cnt, bsum, off, N);
  k_scatter<<<(E + 255) / 256, 256, 0, stream>>>(eidx, eattr, off, ssrc, sattr, E);

  k_agg<<<(N * 64 + 255) / 256, 256, 0, stream>>>(
      h0, h1, ssrc, sattr, off, pb16, gemb, agg, N);

  k_post<<<nb, 256, 0, stream>>>(agg, pb16, d_out, deg);
}